// Round 1
// baseline (29551.981 us; speedup 1.0000x reference)
//
#include <hip/hip_runtime.h>
#include <hip/hip_fp16.h>
#include <math.h>

// Echo-state network: sequential scan with dense 2048x2048 matvec per step.
// R21 -- 8 time-chunks via f16-packed W (halves the sequential round count).
//
// Rationale: the scan is LATENCY-bound (R20 floor statement): round latency
// ~3700cy is dominated by LLC store-visibility + batched detect, and is
// incompressible (R5-R18). The remaining lever is ROUND COUNT. 8 chunks needs
// each chunk's 16MB W in 32 CUs' register files = 256 floats/lane fp32
// (closed by arithmetic), but only 128 dwords/lane as packed f16 -- the SAME
// register footprint as the proven 4-chunk kernel (32 x float4, PIN4 "+v",
// __launch_bounds__(512,2)). R19's bf16 attempt spilled because the packed
// regs landed under a 4-waves/EU arch budget; this keeps the exact (512,2)
// structure that demonstrably holds 128 pinned dwords. f16 (not bf16): 4x
// mantissa at same cost; |W|<=0.12 so range is fine; unpack fuses to
// v_fma_mix_f32. tw bias-fold MUST be computed from the f16-ROUNDED values
// (fp32 tw would inject bias*sum(eps) ~ 1.6e-3/row/step systematic error).
//
// Geometry: 8 chunks x 32 blocks x 512 thr; chunk = blk&7 (one XCD/chunk),
// 64 rows/block, 8 rows/wave, lane holds cols {4l+j+256m} of its 8 rows.
// C0LEN=2104, CLEN=2040, WUP=64 -> uniform NROUND=2104 (vs 4144).
// g0 = 2040*chunk. Warm-up writes land in the previous chunk's tail region
// ~2040 rounds BEFORE the owner rewrites them; parity bias-tags (2/6
// alternating, adjacent chunks differ) reject cross-chunk values exactly as
// in R11-R20. Boundaries are not %16-aligned -> out_kernel computes bias
// per element.
//
// Carried structure (R5/R11/R14/R16): in-loop x load drains with polls;
// block-coop poll (4 dwords/thr), straggler retry, publish to LDS, ONE
// barrier, consume 8x ds_read_b128 vs register W, fold+butterfly reduce
// (10 shfl for 8 rows), tanh, agent-scope store; fc1/fc2 collapse:
// out = states_biased @ Mt + (c2b - bias_t * rm).

#define SS 16384
#define II 64
#define RR 2048
#define HH 128
#define OO 50
#define OP 64          // padded output dim
#define NROUND 2104    // rounds per chunk (uniform)
#define C0LEN 2104     // chunk 0 output length
#define CLEN 2040      // chunks 1-7 output length
#define WUP 64         // warm-up steps for chunks 1-7
#define NBLK 256
#define NTHR 512
#define TT 16          // timesteps per block in out_kernel

static const size_t STATES_BYTES = (size_t)SS * RR * 4;        // 134217728
static const size_t MT_OFF  = STATES_BYTES;
static const size_t C2B_OFF = MT_OFF + (size_t)RR * OP * 4;    // +524288
static const size_t RM_OFF  = C2B_OFF + 256;
static const size_t RS_OFF  = RM_OFF + 256;
static const size_t WS_NEED = RS_OFF + 512 + 256;

// Opaque register pin for LOOP-INVARIANT values (W fragments) only.
// NEVER on in-loop load results (forces a waitcnt at the pin site -- R6/R15).
#define PIN4(q) asm volatile("" : "+v"((q).x), "+v"((q).y), "+v"((q).z), "+v"((q).w))

// ---------------------------------------------------------------------------
// Persistent chunked scan. chunk = blk&7 (XCD affinity), brow = blk>>3.
// Wave w owns rows R0 = brow*64 + w*8 .. R0+7; lane l holds cols
// {4l+j+256m} (j<4, m<8) of its 8 rows, f16-packed 2/dword.
// ---------------------------------------------------------------------------
__global__ __launch_bounds__(NTHR, 2)
void scan_kernel(const float* __restrict__ x,
                 const float* __restrict__ Win,
                 const float* __restrict__ W,
                 float* __restrict__ states)
{
    const int tid   = threadIdx.x;
    const int blk   = blockIdx.x;
    const int wave  = tid >> 6;             // 0..7
    const int lane  = tid & 63;
    const int chunk = blk & 7;              // one XCD per chunk
    const int brow  = blk >> 3;             // 0..31
    const int R0    = brow * 64 + wave * 8;

    const float bias = (chunk & 1) ? 6.0f : 2.0f;
    const int g0 = CLEN * chunk;            // 0 for chunk 0; warm-up start else

    // W fragments: 8 rows x 32 cols = 256 f16 = 128 dwords/lane, pinned.
    // wq[r][k]: {pack(c0,c1) m=2k, pack(c2,c3) m=2k, pack(c0,c1) m=2k+1,
    //            pack(c2,c3) m=2k+1}.  tw from the ROUNDED values.
    float4 wq[8][4];
    float tw[8];
#pragma unroll
    for (int r = 0; r < 8; ++r) {
        float s = 0.f;
#pragma unroll
        for (int k = 0; k < 4; ++k) {
            const size_t base = (size_t)(R0 + r) * RR + 4 * lane;
            const float4 we = *(const float4*)&W[base + 256 * (2 * k)];
            const float4 wo = *(const float4*)&W[base + 256 * (2 * k + 1)];
            const __half2 e01 = __halves2half2(__float2half_rn(we.x), __float2half_rn(we.y));
            const __half2 e23 = __halves2half2(__float2half_rn(we.z), __float2half_rn(we.w));
            const __half2 o01 = __halves2half2(__float2half_rn(wo.x), __float2half_rn(wo.y));
            const __half2 o23 = __halves2half2(__float2half_rn(wo.z), __float2half_rn(wo.w));
            wq[r][k].x = __builtin_bit_cast(float, e01);
            wq[r][k].y = __builtin_bit_cast(float, e23);
            wq[r][k].z = __builtin_bit_cast(float, o01);
            wq[r][k].w = __builtin_bit_cast(float, o23);
            PIN4(wq[r][k]);
            const float2 f0 = __half22float2(e01);
            const float2 f1 = __half22float2(e23);
            const float2 f2 = __half22float2(o01);
            const float2 f3 = __half22float2(o23);
            s += f0.x + f0.y + f1.x + f1.y + f2.x + f2.y + f3.x + f3.y;
        }
        tw[r] = bias * s;
    }
    // Input projection fragments
    float win[8];
#pragma unroll
    for (int r = 0; r < 8; ++r)
        win[r] = Win[(size_t)(R0 + r) * II + lane];

    __shared__ float hbuf[2][RR];   // double-buffered biased h tile

    float hold = 0.f;               // lane tracks row R0 + (lane&7)

    for (int j = 0; j < NROUND; ++j) {
        const int g = g0 + j;
        const float xv = x[(size_t)g * II + lane];  // in-loop: drains with poll
        float acc[8];
#pragma unroll
        for (int r = 0; r < 8; ++r) acc[r] = win[r] * xv;

        if (j > 0) {
            const float* hp = states + (size_t)(g - 1) * RR;
            float* sb = hbuf[(j - 1) & 1];
            // First pass: 4 coalesced dword poll loads per thread.
            float v0 = __hip_atomic_load(hp + tid,
                                         __ATOMIC_RELAXED, __HIP_MEMORY_SCOPE_AGENT);
            float v1 = __hip_atomic_load(hp + tid + 512,
                                         __ATOMIC_RELAXED, __HIP_MEMORY_SCOPE_AGENT);
            float v2 = __hip_atomic_load(hp + tid + 1024,
                                         __ATOMIC_RELAXED, __HIP_MEMORY_SCOPE_AGENT);
            float v3 = __hip_atomic_load(hp + tid + 1536,
                                         __ATOMIC_RELAXED, __HIP_MEMORY_SCOPE_AGENT);
            // Parity-range readiness: accept only my chunk's bias range.
            for (;;) {
                const bool r0 = fabsf(v0 - bias) <= 1.25f;
                const bool r1 = fabsf(v1 - bias) <= 1.25f;
                const bool r2 = fabsf(v2 - bias) <= 1.25f;
                const bool r3 = fabsf(v3 - bias) <= 1.25f;
                if (r0 && r1 && r2 && r3) break;
                if (!r0) v0 = __hip_atomic_load(hp + tid,
                                __ATOMIC_RELAXED, __HIP_MEMORY_SCOPE_AGENT);
                if (!r1) v1 = __hip_atomic_load(hp + tid + 512,
                                __ATOMIC_RELAXED, __HIP_MEMORY_SCOPE_AGENT);
                if (!r2) v2 = __hip_atomic_load(hp + tid + 1024,
                                __ATOMIC_RELAXED, __HIP_MEMORY_SCOPE_AGENT);
                if (!r3) v3 = __hip_atomic_load(hp + tid + 1536,
                                __ATOMIC_RELAXED, __HIP_MEMORY_SCOPE_AGENT);
            }
            // Publish raw biased values (stride-512: 2-way bank alias, free)
            sb[tid]        = v0;
            sb[tid + 512]  = v1;
            sb[tid + 1024] = v2;
            sb[tid + 1536] = v3;
            __syncthreads();           // the ONLY barrier per round

#pragma unroll
            for (int r = 0; r < 8; ++r) acc[r] -= tw[r];

            // Consume: 8 x ds_read_b128 vs register-held f16 W (8 rows).
            // (float)(__half) * f32 -> v_fma_mix_f32.
            const float4* sq = (const float4*)sb;
#pragma unroll
            for (int m = 0; m < 8; ++m) {
                const float4 q = sq[lane + 64 * m];
#pragma unroll
                for (int r = 0; r < 8; ++r) {
                    const float4 wp = wq[r][m >> 1];
                    const float pw0 = (m & 1) ? wp.z : wp.x;
                    const float pw1 = (m & 1) ? wp.w : wp.y;
                    const float2 fA = __half22float2(__builtin_bit_cast(__half2, pw0));
                    const float2 fB = __half22float2(__builtin_bit_cast(__half2, pw1));
                    acc[r] += fA.x * q.x + fA.y * q.y + fB.x * q.z + fB.y * q.w;
                }
            }
        }

        // Reduce 8 rows: 3 fold stages + 3-level butterfly (10 shfls).
        {
            const float u01 = ((lane & 1) ? acc[1] : acc[0])
                            + __shfl_xor((lane & 1) ? acc[0] : acc[1], 1, 64);
            const float u23 = ((lane & 1) ? acc[3] : acc[2])
                            + __shfl_xor((lane & 1) ? acc[2] : acc[3], 1, 64);
            const float u45 = ((lane & 1) ? acc[5] : acc[4])
                            + __shfl_xor((lane & 1) ? acc[4] : acc[5], 1, 64);
            const float u67 = ((lane & 1) ? acc[7] : acc[6])
                            + __shfl_xor((lane & 1) ? acc[6] : acc[7], 1, 64);
            const float v03 = ((lane & 2) ? u23 : u01)
                            + __shfl_xor((lane & 2) ? u01 : u23, 2, 64);
            const float v47 = ((lane & 2) ? u67 : u45)
                            + __shfl_xor((lane & 2) ? u45 : u67, 2, 64);
            float a = ((lane & 4) ? v47 : v03)
                    + __shfl_xor((lane & 4) ? v03 : v47, 4, 64);
#pragma unroll
            for (int off = 8; off <= 32; off <<= 1)
                a += __shfl_xor(a, off, 64);
            // tanh + leaky update for row R0 + (lane&7)
            float u = fminf(fmaxf(a, -20.f), 20.f);
            const float e  = __expf(2.f * u);
            const float th = (e - 1.f) / (e + 1.f);
            const float hn = 0.5f * hold + 0.5f * th;
            hold = hn;
            if (lane < 8)
                __hip_atomic_store(&states[(size_t)g * RR + R0 + lane], hn + bias,
                                   __ATOMIC_RELAXED, __HIP_MEMORY_SCOPE_AGENT);
        }
    }
}

// ---------------------------------------------------------------------------
// rowsum of fc1_w rows: rs[h] = sum_r fc1_w[h][r]
// ---------------------------------------------------------------------------
__global__ void k_rowsum(const float* __restrict__ fc1w, float* __restrict__ rs)
{
    const int h = blockIdx.x;
    const int tid = threadIdx.x;
    float a = 0.f;
    for (int r = tid; r < RR; r += 256) a += fc1w[(size_t)h * RR + r];
#pragma unroll
    for (int off = 1; off <= 32; off <<= 1) a += __shfl_xor(a, off, 64);
    __shared__ float red[4];
    if ((tid & 63) == 0) red[tid >> 6] = a;
    __syncthreads();
    if (tid == 0) rs[h] = red[0] + red[1] + red[2] + red[3];
}

// ---------------------------------------------------------------------------
// Mt[r][o] = sum_h fc2_w[o][h] * fc1_w[h][r]   (o padded to 64, zeros)
// ---------------------------------------------------------------------------
__global__ void k_mt(const float* __restrict__ fc1w,
                     const float* __restrict__ fc2w,
                     float* __restrict__ Mt)
{
    __shared__ float w2[OO][HH + 1];
    const int o = threadIdx.x;         // 64
    const int r = blockIdx.x;          // 2048
    for (int i = o; i < OO * HH; i += 64) w2[i / HH][i % HH] = fc2w[i];
    __syncthreads();
    float a = 0.f;
    if (o < OO) {
        for (int h = 0; h < HH; ++h)
            a += w2[o][h] * fc1w[(size_t)h * RR + r];
    }
    Mt[r * OP + o] = a;
}

// ---------------------------------------------------------------------------
// c2b[o] = fc2_b[o] + sum_h fc2_w[o][h]*fc1_b[h];  rm[o] = sum_h fc2w*rs[h]
// ---------------------------------------------------------------------------
__global__ void k_cc(const float* __restrict__ fc2w,
                     const float* __restrict__ fc2b,
                     const float* __restrict__ fc1b,
                     const float* __restrict__ rs,
                     float* __restrict__ c2b,
                     float* __restrict__ rm)
{
    const int o = threadIdx.x;  // 64
    float a = 0.f, b = 0.f;
    if (o < OO) {
        for (int h = 0; h < HH; ++h) {
            a += fc2w[o * HH + h] * fc1b[h];
            b += fc2w[o * HH + h] * rs[h];
        }
        a += fc2b[o];
    }
    c2b[o] = a;
    rm[o]  = b;
}

// ---------------------------------------------------------------------------
// out[t][o] = sum_r Mt[r][o] * states_biased[t][r] + c2b[o] - bias_t*rm[o]
// Chunk boundaries (2104 + 2040k) are NOT %16-aligned -> bias per element.
// ---------------------------------------------------------------------------
__global__ __launch_bounds__(256)
void out_kernel(const float* __restrict__ sb,
                const float* __restrict__ Mt,
                const float* __restrict__ c2b,
                const float* __restrict__ rm,
                float* __restrict__ out)
{
    const int tid = threadIdx.x;
    const int o   = tid & 63;
    const int tl  = tid >> 6;          // 0..3
    const int t0  = blockIdx.x * TT;
    float acc[4] = {0.f, 0.f, 0.f, 0.f};
    const float* s0 = sb + (size_t)t0 * RR;

    for (int r = 0; r < RR; r += 4) {
        float4 sv0 = *(const float4*)(s0 + (size_t)(tl + 0)  * RR + r);
        float4 sv1 = *(const float4*)(s0 + (size_t)(tl + 4)  * RR + r);
        float4 sv2 = *(const float4*)(s0 + (size_t)(tl + 8)  * RR + r);
        float4 sv3 = *(const float4*)(s0 + (size_t)(tl + 12) * RR + r);
        float m0 = Mt[(r + 0) * OP + o];
        float m1 = Mt[(r + 1) * OP + o];
        float m2 = Mt[(r + 2) * OP + o];
        float m3 = Mt[(r + 3) * OP + o];
        acc[0] += m0 * sv0.x + m1 * sv0.y + m2 * sv0.z + m3 * sv0.w;
        acc[1] += m0 * sv1.x + m1 * sv1.y + m2 * sv1.z + m3 * sv1.w;
        acc[2] += m0 * sv2.x + m1 * sv2.y + m2 * sv2.z + m3 * sv2.w;
        acc[3] += m0 * sv3.x + m1 * sv3.y + m2 * sv3.z + m3 * sv3.w;
    }
    if (o < OO) {
        const float cb = c2b[o];
        const float rv = rm[o];
#pragma unroll
        for (int m = 0; m < 4; ++m) {
            const int t = t0 + tl + 4 * m;
            const int ch = (t < C0LEN) ? 0 : (1 + (t - C0LEN) / CLEN);
            const float bias = (ch & 1) ? 6.0f : 2.0f;
            out[(size_t)t * OO + o] = acc[m] + cb - bias * rv;
        }
    }
}

extern "C" void kernel_launch(void* const* d_in, const int* in_sizes, int n_in,
                              void* d_out, int out_size, void* d_ws, size_t ws_size,
                              hipStream_t stream)
{
    const float* x    = (const float*)d_in[0];
    const float* Win  = (const float*)d_in[1];
    const float* W    = (const float*)d_in[2];
    const float* fc1w = (const float*)d_in[3];
    const float* fc1b = (const float*)d_in[4];
    const float* fc2w = (const float*)d_in[5];
    const float* fc2b = (const float*)d_in[6];
    float* out = (float*)d_out;

    if (ws_size < WS_NEED) return;

    char*  ws     = (char*)d_ws;
    float* states = (float*)ws;
    float* Mt     = (float*)(ws + MT_OFF);
    float* c2b    = (float*)(ws + C2B_OFF);
    float* rm     = (float*)(ws + RM_OFF);
    float* rs     = (float*)(ws + RS_OFF);

    // Sentinel init: 0.0f is outside both bias ranges -> "not ready".
    hipMemsetAsync(states, 0, STATES_BYTES, stream);

    k_rowsum<<<HH, 256, 0, stream>>>(fc1w, rs);
    k_mt<<<RR, 64, 0, stream>>>(fc1w, fc2w, Mt);
    k_cc<<<1, 64, 0, stream>>>(fc2w, fc2b, fc1b, rs, c2b, rm);

    scan_kernel<<<NBLK, NTHR, 0, stream>>>(x, Win, W, states);

    out_kernel<<<SS / TT, 256, 0, stream>>>(states, Mt, c2b, rm, out);
}

// Round 2
// 7995.742 us; speedup vs baseline: 3.6960x; 3.6960x over previous
//
#include <hip/hip_runtime.h>
#include <hip/hip_fp16.h>
#include <math.h>

// Echo-state network: sequential scan with dense 2048x2048 matvec per step.
// R22 -- 8 time-chunks via hybrid W storage: 4 rows/wave in fp32 REGISTERS
// (byte-identical to the proven R16/R20 structure) + 4 rows/wave in f16 LDS.
//
// R21 post-mortem: f16-packed W (256 cols/lane in 128 dwords) spilled to
// SCRATCH, not AGPRs -- VGPR_Count=128, VALUBusy 34->6%, FETCH 0.18->49.8GB
// (67MB/round spill re-stream; 8MB/XCD scratch > 4MB L2). The all-register
// 256-col path is 0-for-2 (R19 bf16, R21 f16) on register-class allocation.
// BUT R21 proved: (a) 8-chunk geometry + parity protocol is CORRECT (passed);
// (b) f16-rounded W is numerically free (absmax bit-identical, 0.001953).
//
// R22 keeps the round-count halving (4144 -> 2104 sequential rounds) and
// fixes storage: registers hold EXACTLY what the baseline proved they hold
// (4 rows x 8 float4 = 128 fp32 dwords, PIN4 "+v", lives in AGPRs at
// VGPR~100); rows 4..7 of each wave live in LDS as packed f16:
// 32 rows x 2048 x 2B = 128KB + 16KB hbuf = 144KB dynamic LDS.
// Each wave stages and consumes ONLY its own LDS rows -> no extra barrier.
// Consume adds 4x ds_read_b64 (contiguous, conflict-free) + 16x
// v_fma_mix_f32 per m-step; h stays fp32 everywhere.
// Bias-fold tw[8] pre-reduced at init to ONE register (twred), subtracted
// post-butterfly (j>0 only) -- saves 7 regs, removes 8 VALU/round.
//
// Cost model: LDS pipe 136KB -> 392KB per round per CU (+~1000cy);
// round ~3700 -> ~4700-5200cy; 2104 rounds -> ~4.1-4.6ms (vs 6.39ms).
//
// Carried structure (R5/R11/R14/R16/R21): in-loop x load drains with polls;
// block-coop poll (4 dwords/thr), straggler retry, publish to LDS, ONE
// barrier, consume vs register/LDS W, fold+butterfly reduce, tanh,
// agent-scope store; fc1/fc2 collapse: out = states_b @ Mt + (c2b - bias*rm).

#define SS 16384
#define II 64
#define RR 2048
#define HH 128
#define OO 50
#define OP 64          // padded output dim
#define NROUND 2104    // rounds per chunk (uniform)
#define C0LEN 2104     // chunk 0 output length
#define CLEN 2040      // chunks 1-7 output length
#define WUP 64         // warm-up steps for chunks 1-7
#define NBLK 256
#define NTHR 512
#define TT 16          // timesteps per block in out_kernel

#define SMEM_BYTES (2 * RR * 4 + 32 * RR * 2)   // 16384 + 131072 = 147456

static const size_t STATES_BYTES = (size_t)SS * RR * 4;        // 134217728
static const size_t MT_OFF  = STATES_BYTES;
static const size_t C2B_OFF = MT_OFF + (size_t)RR * OP * 4;    // +524288
static const size_t RM_OFF  = C2B_OFF + 256;
static const size_t RS_OFF  = RM_OFF + 256;
static const size_t WS_NEED = RS_OFF + 512 + 256;

// Opaque register pin for LOOP-INVARIANT values (W fragments) only.
// NEVER on in-loop load results (forces a waitcnt at the pin site -- R6/R15).
#define PIN4(q) asm volatile("" : "+v"((q).x), "+v"((q).y), "+v"((q).z), "+v"((q).w))

// ---------------------------------------------------------------------------
// Persistent chunked scan. chunk = blk&7 (one XCD per chunk), brow = blk>>3.
// Wave w owns rows R0 = brow*64 + w*8 .. R0+7.
//   rows R0+0..3: fp32 in registers, lane l holds cols {4l+j+256m}.
//   rows R0+4..7: f16 in LDS, same column mapping, wave-private.
// ---------------------------------------------------------------------------
__global__ __launch_bounds__(NTHR, 2)
void scan_kernel(const float* __restrict__ x,
                 const float* __restrict__ Win,
                 const float* __restrict__ W,
                 float* __restrict__ states)
{
    const int tid   = threadIdx.x;
    const int blk   = blockIdx.x;
    const int wave  = tid >> 6;             // 0..7
    const int lane  = tid & 63;
    const int chunk = blk & 7;              // one XCD per chunk
    const int brow  = blk >> 3;             // 0..31
    const int R0    = brow * 64 + wave * 8;

    const float bias = (chunk & 1) ? 6.0f : 2.0f;
    const int g0 = CLEN * chunk;            // 0 for chunk 0; warm-up start else

    extern __shared__ char smem_raw[];
    float* hb  = (float*)smem_raw;                       // [2][RR]
    uint2* wl2 = (uint2*)(smem_raw + 2 * RR * 4);        // 32 rows x 512 uint2

    // --- Register W: rows 0..3, byte-identical to proven baseline ---
    float4 wq[4][8];
#pragma unroll
    for (int r = 0; r < 4; ++r)
#pragma unroll
        for (int m = 0; m < 8; ++m) {
            wq[r][m] = *(const float4*)&W[(size_t)(R0 + r) * RR + 4 * lane + 256 * m];
            PIN4(wq[r][m]);
        }

    // Per-row bias-fold partials (reg rows: exact fp32 values)
    float twp[8];
#pragma unroll
    for (int r = 0; r < 4; ++r) {
        float s = 0.f;
#pragma unroll
        for (int m = 0; m < 8; ++m)
            s += wq[r][m].x + wq[r][m].y + wq[r][m].z + wq[r][m].w;
        twp[r] = s;
    }

    // --- LDS W: rows 4..7, packed f16, wave-private (no barrier needed) ---
    const int wrow = wave * 4;              // my first LDS row slot
#pragma unroll
    for (int rr = 0; rr < 4; ++rr) {
        float s = 0.f;
#pragma unroll
        for (int m = 0; m < 8; ++m) {
            const float4 wv = *(const float4*)&W[(size_t)(R0 + 4 + rr) * RR + 4 * lane + 256 * m];
            const __half h0 = __float2half_rn(wv.x);
            const __half h1 = __float2half_rn(wv.y);
            const __half h2 = __float2half_rn(wv.z);
            const __half h3 = __float2half_rn(wv.w);
            uint2 p;
            p.x = __builtin_bit_cast(unsigned int, __halves2half2(h0, h1));
            p.y = __builtin_bit_cast(unsigned int, __halves2half2(h2, h3));
            wl2[(size_t)(wrow + rr) * 512 + lane + 64 * m] = p;
            // tw from the ROUNDED values (what the dot product will use)
            s += __half2float(h0) + __half2float(h1)
               + __half2float(h2) + __half2float(h3);
        }
        twp[4 + rr] = s;
    }

    // Pre-reduce tw across lanes with the SAME fold+butterfly as the main
    // loop: after this, every lane holds bias * rowsum(W[R0+(lane&7)]).
    float twred;
    {
        const float u01 = ((lane & 1) ? twp[1] : twp[0])
                        + __shfl_xor((lane & 1) ? twp[0] : twp[1], 1, 64);
        const float u23 = ((lane & 1) ? twp[3] : twp[2])
                        + __shfl_xor((lane & 1) ? twp[2] : twp[3], 1, 64);
        const float u45 = ((lane & 1) ? twp[5] : twp[4])
                        + __shfl_xor((lane & 1) ? twp[4] : twp[5], 1, 64);
        const float u67 = ((lane & 1) ? twp[7] : twp[6])
                        + __shfl_xor((lane & 1) ? twp[6] : twp[7], 1, 64);
        const float v03 = ((lane & 2) ? u23 : u01)
                        + __shfl_xor((lane & 2) ? u01 : u23, 2, 64);
        const float v47 = ((lane & 2) ? u67 : u45)
                        + __shfl_xor((lane & 2) ? u45 : u67, 2, 64);
        float a = ((lane & 4) ? v47 : v03)
                + __shfl_xor((lane & 4) ? v03 : v47, 4, 64);
#pragma unroll
        for (int off = 8; off <= 32; off <<= 1)
            a += __shfl_xor(a, off, 64);
        twred = bias * a;
    }

    // Input projection fragments
    float win[8];
#pragma unroll
    for (int r = 0; r < 8; ++r)
        win[r] = Win[(size_t)(R0 + r) * II + lane];

    float hold = 0.f;               // lane tracks row R0 + (lane&7)

    for (int j = 0; j < NROUND; ++j) {
        const int g = g0 + j;
        const float xv = x[(size_t)g * II + lane];  // in-loop: drains with poll
        float acc[8];
#pragma unroll
        for (int r = 0; r < 8; ++r) acc[r] = win[r] * xv;

        if (j > 0) {
            const float* hp = states + (size_t)(g - 1) * RR;
            float* sb = hb + ((j - 1) & 1) * RR;
            // First pass: 4 coalesced dword poll loads per thread.
            float v0 = __hip_atomic_load(hp + tid,
                                         __ATOMIC_RELAXED, __HIP_MEMORY_SCOPE_AGENT);
            float v1 = __hip_atomic_load(hp + tid + 512,
                                         __ATOMIC_RELAXED, __HIP_MEMORY_SCOPE_AGENT);
            float v2 = __hip_atomic_load(hp + tid + 1024,
                                         __ATOMIC_RELAXED, __HIP_MEMORY_SCOPE_AGENT);
            float v3 = __hip_atomic_load(hp + tid + 1536,
                                         __ATOMIC_RELAXED, __HIP_MEMORY_SCOPE_AGENT);
            // Parity-range readiness: accept only my chunk's bias range.
            for (;;) {
                const bool r0 = fabsf(v0 - bias) <= 1.25f;
                const bool r1 = fabsf(v1 - bias) <= 1.25f;
                const bool r2 = fabsf(v2 - bias) <= 1.25f;
                const bool r3 = fabsf(v3 - bias) <= 1.25f;
                if (r0 && r1 && r2 && r3) break;
                if (!r0) v0 = __hip_atomic_load(hp + tid,
                                __ATOMIC_RELAXED, __HIP_MEMORY_SCOPE_AGENT);
                if (!r1) v1 = __hip_atomic_load(hp + tid + 512,
                                __ATOMIC_RELAXED, __HIP_MEMORY_SCOPE_AGENT);
                if (!r2) v2 = __hip_atomic_load(hp + tid + 1024,
                                __ATOMIC_RELAXED, __HIP_MEMORY_SCOPE_AGENT);
                if (!r3) v3 = __hip_atomic_load(hp + tid + 1536,
                                __ATOMIC_RELAXED, __HIP_MEMORY_SCOPE_AGENT);
            }
            // Publish raw biased values (stride-512: 2-way bank alias, free)
            sb[tid]        = v0;
            sb[tid + 512]  = v1;
            sb[tid + 1024] = v2;
            sb[tid + 1536] = v3;
            __syncthreads();           // the ONLY barrier per round

            // Consume: 8x ds_read_b128 (h) vs register W (rows 0..3) and
            // 32x ds_read_b64 (f16 W) vs fp32 h (rows 4..7, v_fma_mix).
            const float4* sq = (const float4*)sb;
#pragma unroll
            for (int m = 0; m < 8; ++m) {
                const float4 q = sq[lane + 64 * m];
                acc[0] += wq[0][m].x * q.x + wq[0][m].y * q.y
                        + wq[0][m].z * q.z + wq[0][m].w * q.w;
                acc[1] += wq[1][m].x * q.x + wq[1][m].y * q.y
                        + wq[1][m].z * q.z + wq[1][m].w * q.w;
                acc[2] += wq[2][m].x * q.x + wq[2][m].y * q.y
                        + wq[2][m].z * q.z + wq[2][m].w * q.w;
                acc[3] += wq[3][m].x * q.x + wq[3][m].y * q.y
                        + wq[3][m].z * q.z + wq[3][m].w * q.w;
#pragma unroll
                for (int rr = 0; rr < 4; ++rr) {
                    const uint2 wp = wl2[(size_t)(wrow + rr) * 512 + lane + 64 * m];
                    const __half2 wa = __builtin_bit_cast(__half2, wp.x);
                    const __half2 wb = __builtin_bit_cast(__half2, wp.y);
                    acc[4 + rr] += __low2float(wa)  * q.x + __high2float(wa) * q.y
                                 + __low2float(wb)  * q.z + __high2float(wb) * q.w;
                }
            }
        }

        // Reduce 8 rows: 3 fold stages + 3-level butterfly (10 shfls).
        {
            const float u01 = ((lane & 1) ? acc[1] : acc[0])
                            + __shfl_xor((lane & 1) ? acc[0] : acc[1], 1, 64);
            const float u23 = ((lane & 1) ? acc[3] : acc[2])
                            + __shfl_xor((lane & 1) ? acc[2] : acc[3], 1, 64);
            const float u45 = ((lane & 1) ? acc[5] : acc[4])
                            + __shfl_xor((lane & 1) ? acc[4] : acc[5], 1, 64);
            const float u67 = ((lane & 1) ? acc[7] : acc[6])
                            + __shfl_xor((lane & 1) ? acc[6] : acc[7], 1, 64);
            const float v03 = ((lane & 2) ? u23 : u01)
                            + __shfl_xor((lane & 2) ? u01 : u23, 2, 64);
            const float v47 = ((lane & 2) ? u67 : u45)
                            + __shfl_xor((lane & 2) ? u45 : u67, 2, 64);
            float a = ((lane & 4) ? v47 : v03)
                    + __shfl_xor((lane & 4) ? v03 : v47, 4, 64);
#pragma unroll
            for (int off = 8; off <= 32; off <<= 1)
                a += __shfl_xor(a, off, 64);
            // Bias-fold correction (only when biased h was consumed)
            if (j > 0) a -= twred;
            // tanh + leaky update for row R0 + (lane&7)
            float u = fminf(fmaxf(a, -20.f), 20.f);
            const float e  = __expf(2.f * u);
            const float th = (e - 1.f) / (e + 1.f);
            const float hn = 0.5f * hold + 0.5f * th;
            hold = hn;
            if (lane < 8)
                __hip_atomic_store(&states[(size_t)g * RR + R0 + lane], hn + bias,
                                   __ATOMIC_RELAXED, __HIP_MEMORY_SCOPE_AGENT);
        }
    }
}

// ---------------------------------------------------------------------------
// rowsum of fc1_w rows: rs[h] = sum_r fc1_w[h][r]
// ---------------------------------------------------------------------------
__global__ void k_rowsum(const float* __restrict__ fc1w, float* __restrict__ rs)
{
    const int h = blockIdx.x;
    const int tid = threadIdx.x;
    float a = 0.f;
    for (int r = tid; r < RR; r += 256) a += fc1w[(size_t)h * RR + r];
#pragma unroll
    for (int off = 1; off <= 32; off <<= 1) a += __shfl_xor(a, off, 64);
    __shared__ float red[4];
    if ((tid & 63) == 0) red[tid >> 6] = a;
    __syncthreads();
    if (tid == 0) rs[h] = red[0] + red[1] + red[2] + red[3];
}

// ---------------------------------------------------------------------------
// Mt[r][o] = sum_h fc2_w[o][h] * fc1_w[h][r]   (o padded to 64, zeros)
// ---------------------------------------------------------------------------
__global__ void k_mt(const float* __restrict__ fc1w,
                     const float* __restrict__ fc2w,
                     float* __restrict__ Mt)
{
    __shared__ float w2[OO][HH + 1];
    const int o = threadIdx.x;         // 64
    const int r = blockIdx.x;          // 2048
    for (int i = o; i < OO * HH; i += 64) w2[i / HH][i % HH] = fc2w[i];
    __syncthreads();
    float a = 0.f;
    if (o < OO) {
        for (int h = 0; h < HH; ++h)
            a += w2[o][h] * fc1w[(size_t)h * RR + r];
    }
    Mt[r * OP + o] = a;
}

// ---------------------------------------------------------------------------
// c2b[o] = fc2_b[o] + sum_h fc2_w[o][h]*fc1_b[h];  rm[o] = sum_h fc2w*rs[h]
// ---------------------------------------------------------------------------
__global__ void k_cc(const float* __restrict__ fc2w,
                     const float* __restrict__ fc2b,
                     const float* __restrict__ fc1b,
                     const float* __restrict__ rs,
                     float* __restrict__ c2b,
                     float* __restrict__ rm)
{
    const int o = threadIdx.x;  // 64
    float a = 0.f, b = 0.f;
    if (o < OO) {
        for (int h = 0; h < HH; ++h) {
            a += fc2w[o * HH + h] * fc1b[h];
            b += fc2w[o * HH + h] * rs[h];
        }
        a += fc2b[o];
    }
    c2b[o] = a;
    rm[o]  = b;
}

// ---------------------------------------------------------------------------
// out[t][o] = sum_r Mt[r][o] * states_biased[t][r] + c2b[o] - bias_t*rm[o]
// Chunk boundaries (2104 + 2040k) are NOT %16-aligned -> bias per element.
// ---------------------------------------------------------------------------
__global__ __launch_bounds__(256)
void out_kernel(const float* __restrict__ sb,
                const float* __restrict__ Mt,
                const float* __restrict__ c2b,
                const float* __restrict__ rm,
                float* __restrict__ out)
{
    const int tid = threadIdx.x;
    const int o   = tid & 63;
    const int tl  = tid >> 6;          // 0..3
    const int t0  = blockIdx.x * TT;
    float acc[4] = {0.f, 0.f, 0.f, 0.f};
    const float* s0 = sb + (size_t)t0 * RR;

    for (int r = 0; r < RR; r += 4) {
        float4 sv0 = *(const float4*)(s0 + (size_t)(tl + 0)  * RR + r);
        float4 sv1 = *(const float4*)(s0 + (size_t)(tl + 4)  * RR + r);
        float4 sv2 = *(const float4*)(s0 + (size_t)(tl + 8)  * RR + r);
        float4 sv3 = *(const float4*)(s0 + (size_t)(tl + 12) * RR + r);
        float m0 = Mt[(r + 0) * OP + o];
        float m1 = Mt[(r + 1) * OP + o];
        float m2 = Mt[(r + 2) * OP + o];
        float m3 = Mt[(r + 3) * OP + o];
        acc[0] += m0 * sv0.x + m1 * sv0.y + m2 * sv0.z + m3 * sv0.w;
        acc[1] += m0 * sv1.x + m1 * sv1.y + m2 * sv1.z + m3 * sv1.w;
        acc[2] += m0 * sv2.x + m1 * sv2.y + m2 * sv2.z + m3 * sv2.w;
        acc[3] += m0 * sv3.x + m1 * sv3.y + m2 * sv3.z + m3 * sv3.w;
    }
    if (o < OO) {
        const float cb = c2b[o];
        const float rv = rm[o];
#pragma unroll
        for (int m = 0; m < 4; ++m) {
            const int t = t0 + tl + 4 * m;
            const int ch = (t < C0LEN) ? 0 : (1 + (t - C0LEN) / CLEN);
            const float bias = (ch & 1) ? 6.0f : 2.0f;
            out[(size_t)t * OO + o] = acc[m] + cb - bias * rv;
        }
    }
}

extern "C" void kernel_launch(void* const* d_in, const int* in_sizes, int n_in,
                              void* d_out, int out_size, void* d_ws, size_t ws_size,
                              hipStream_t stream)
{
    const float* x    = (const float*)d_in[0];
    const float* Win  = (const float*)d_in[1];
    const float* W    = (const float*)d_in[2];
    const float* fc1w = (const float*)d_in[3];
    const float* fc1b = (const float*)d_in[4];
    const float* fc2w = (const float*)d_in[5];
    const float* fc2b = (const float*)d_in[6];
    float* out = (float*)d_out;

    if (ws_size < WS_NEED) return;

    char*  ws     = (char*)d_ws;
    float* states = (float*)ws;
    float* Mt     = (float*)(ws + MT_OFF);
    float* c2b    = (float*)(ws + C2B_OFF);
    float* rm     = (float*)(ws + RM_OFF);
    float* rs     = (float*)(ws + RS_OFF);

    // Raise the dynamic-LDS cap once (not a stream op; graph-capture safe).
    static bool attr_done = false;
    if (!attr_done) {
        hipFuncSetAttribute(reinterpret_cast<const void*>(scan_kernel),
                            hipFuncAttributeMaxDynamicSharedMemorySize,
                            SMEM_BYTES);
        attr_done = true;
    }

    // Sentinel init: 0.0f is outside both bias ranges -> "not ready".
    hipMemsetAsync(states, 0, STATES_BYTES, stream);

    k_rowsum<<<HH, 256, 0, stream>>>(fc1w, rs);
    k_mt<<<RR, 64, 0, stream>>>(fc1w, fc2w, Mt);
    k_cc<<<1, 64, 0, stream>>>(fc2w, fc2b, fc1b, rs, c2b, rm);

    scan_kernel<<<NBLK, NTHR, SMEM_BYTES, stream>>>(x, Win, W, states);

    out_kernel<<<SS / TT, 256, 0, stream>>>(states, Mt, c2b, rm, out);
}

// Round 4
// 6537.416 us; speedup vs baseline: 4.5204x; 1.2231x over previous
//
#include <hip/hip_runtime.h>
#include <hip/hip_fp16.h>
#include <math.h>

// Echo-state network: sequential scan with dense 2048x2048 matvec per step.
// R24 -- R22 structure with the consume phase repaired via v_dot2_f32_f16.
//
// R23 post-mortem (crash, no counters): three unproven constructs at once
// (inline-asm sc0 loads, raw s_getreg hwreg, +4MB ws) -- any could compile-
// abort or hang. All reverted; transport is back to the R22-proven
// agent-scope protocol. No probe, no scratch, R22 ws layout.
//
// R22 post-mortem (passed, 8.08ms): VALUBusy x dur = 1.33us VALU/round vs
// R20's 0.53us -- the f16 unpack (__low2float + mul/add chains) did NOT
// fuse into v_fma_mix; consume VALU tripled and ate the round-halving.
// R24 fixes instruction selection with a guaranteed builtin:
// __builtin_amdgcn_fdot2 -> v_dot2_f32_f16 (2 MACs/inst, f32 accumulate).
// Requires h as f16 pairs -> publish also writes a f16 mirror of h
// (4x v_cvt_f16_f32 + 4x ds_write_b16 per thread; +8KB LDS dbuf;
// total 155648 B <= 160KiB). f16-h touches only rows 4..7's contribution:
// ~1e-4 pre-tanh/step -> ~7e-5 at out, negligible vs passing 0.00195.
//
// Per-round model: VALU 8m x (16 fma + 8 fdot2) ~ 290 inst ~ 0.48us;
// LDS pipe 448B/thr ~ 0.77us (overlapped); transport ~0.95us ->
// round ~1.9-2.2us (vs 3.84) -> scan ~4.0-4.6ms.
//
// Carried from R22: 8 chunks x 32 blocks x 512 thr; rows 0..3/wave fp32 in
// regs (PIN4, proven AGPR placement), rows 4..7/wave f16 in LDS; twred
// bias-fold post-butterfly; C0LEN=2104/CLEN=2040/WUP=64 -> NROUND=2104;
// parity bias-tags 2/6; in-loop x load; block-coop agent poll + straggler
// retry; publish + ONE barrier; fold+butterfly reduce; tanh; agent store;
// fc1/fc2 collapse: out = states_biased @ Mt + (c2b - bias_t * rm).

#define SS 16384
#define II 64
#define RR 2048
#define HH 128
#define OO 50
#define OP 64          // padded output dim
#define NROUND 2104    // rounds per chunk (uniform)
#define C0LEN 2104     // chunk 0 output length
#define CLEN 2040      // chunks 1-7 output length
#define WUP 64         // warm-up steps for chunks 1-7
#define NBLK 256
#define NTHR 512
#define TT 16          // timesteps per block in out_kernel

// hbuf f32 dbuf (16KB) + W f16 rows (128KB) + hbuf f16 dbuf (8KB)
#define SMEM_BYTES (2 * RR * 4 + 32 * RR * 2 + 2 * RR * 2)   // 155648

static const size_t STATES_BYTES = (size_t)SS * RR * 4;        // 134217728
static const size_t MT_OFF  = STATES_BYTES;
static const size_t C2B_OFF = MT_OFF + (size_t)RR * OP * 4;    // +524288
static const size_t RM_OFF  = C2B_OFF + 256;
static const size_t RS_OFF  = RM_OFF + 256;
static const size_t WS_NEED = RS_OFF + 512 + 256;

typedef _Float16 h2v __attribute__((ext_vector_type(2)));

// Opaque register pin for LOOP-INVARIANT values (W fragments) only.
// NEVER on in-loop load results (forces a waitcnt at the pin site -- R6/R15).
#define PIN4(q) asm volatile("" : "+v"((q).x), "+v"((q).y), "+v"((q).z), "+v"((q).w))

// ---------------------------------------------------------------------------
// Persistent chunked scan. chunk = blk&7, brow = blk>>3.
// Wave w owns rows R0 = brow*64 + w*8 .. R0+7.
//   rows R0+0..3: fp32 in registers, lane l holds cols {4l+j+256m}.
//   rows R0+4..7: f16 in LDS, same column mapping, wave-private.
// ---------------------------------------------------------------------------
__global__ __launch_bounds__(NTHR, 2)
void scan_kernel(const float* __restrict__ x,
                 const float* __restrict__ Win,
                 const float* __restrict__ W,
                 float* __restrict__ states)
{
    const int tid   = threadIdx.x;
    const int blk   = blockIdx.x;
    const int wave  = tid >> 6;             // 0..7
    const int lane  = tid & 63;
    const int chunk = blk & 7;
    const int brow  = blk >> 3;             // 0..31
    const int R0    = brow * 64 + wave * 8;

    const float bias = (chunk & 1) ? 6.0f : 2.0f;
    const int g0 = CLEN * chunk;            // 0 for chunk 0; warm-up start else

    extern __shared__ char smem_raw[];
    float*    hb   = (float*)smem_raw;                          // [2][RR] f32
    uint2*    wl2  = (uint2*)(smem_raw + 2 * RR * 4);           // 32 x 512 uint2
    _Float16* h16  = (_Float16*)(smem_raw + 2 * RR * 4 + 32 * RR * 2); // [2][RR]

    // --- Register W: rows 0..3, byte-identical to proven baseline ---
    float4 wq[4][8];
#pragma unroll
    for (int r = 0; r < 4; ++r)
#pragma unroll
        for (int m = 0; m < 8; ++m) {
            wq[r][m] = *(const float4*)&W[(size_t)(R0 + r) * RR + 4 * lane + 256 * m];
            PIN4(wq[r][m]);
        }

    // Per-row bias-fold partials (reg rows: exact fp32 values)
    float twp[8];
#pragma unroll
    for (int r = 0; r < 4; ++r) {
        float s = 0.f;
#pragma unroll
        for (int m = 0; m < 8; ++m)
            s += wq[r][m].x + wq[r][m].y + wq[r][m].z + wq[r][m].w;
        twp[r] = s;
    }

    // --- LDS W: rows 4..7, packed f16, wave-private (no barrier needed) ---
    const int wrow = wave * 4;              // my first LDS row slot
#pragma unroll
    for (int rr = 0; rr < 4; ++rr) {
        float s = 0.f;
#pragma unroll
        for (int m = 0; m < 8; ++m) {
            const float4 wv = *(const float4*)&W[(size_t)(R0 + 4 + rr) * RR + 4 * lane + 256 * m];
            const __half h0 = __float2half_rn(wv.x);
            const __half h1 = __float2half_rn(wv.y);
            const __half h2 = __float2half_rn(wv.z);
            const __half h3 = __float2half_rn(wv.w);
            uint2 p;
            p.x = __builtin_bit_cast(unsigned int, __halves2half2(h0, h1));
            p.y = __builtin_bit_cast(unsigned int, __halves2half2(h2, h3));
            wl2[(size_t)(wrow + rr) * 512 + lane + 64 * m] = p;
            // tw from the ROUNDED values (what the dot product will use)
            s += __half2float(h0) + __half2float(h1)
               + __half2float(h2) + __half2float(h3);
        }
        twp[4 + rr] = s;
    }

    // Pre-reduce tw across lanes with the SAME fold+butterfly as the main
    // loop: after this, every lane holds bias * rowsum(W[R0+(lane&7)]).
    float twred;
    {
        const float u01 = ((lane & 1) ? twp[1] : twp[0])
                        + __shfl_xor((lane & 1) ? twp[0] : twp[1], 1, 64);
        const float u23 = ((lane & 1) ? twp[3] : twp[2])
                        + __shfl_xor((lane & 1) ? twp[2] : twp[3], 1, 64);
        const float u45 = ((lane & 1) ? twp[5] : twp[4])
                        + __shfl_xor((lane & 1) ? twp[4] : twp[5], 1, 64);
        const float u67 = ((lane & 1) ? twp[7] : twp[6])
                        + __shfl_xor((lane & 1) ? twp[6] : twp[7], 1, 64);
        const float v03 = ((lane & 2) ? u23 : u01)
                        + __shfl_xor((lane & 2) ? u01 : u23, 2, 64);
        const float v47 = ((lane & 2) ? u67 : u45)
                        + __shfl_xor((lane & 2) ? u45 : u67, 2, 64);
        float a = ((lane & 4) ? v47 : v03)
                + __shfl_xor((lane & 4) ? v03 : v47, 4, 64);
#pragma unroll
        for (int off = 8; off <= 32; off <<= 1)
            a += __shfl_xor(a, off, 64);
        twred = bias * a;
    }

    // Input projection fragments
    float win[8];
#pragma unroll
    for (int r = 0; r < 8; ++r)
        win[r] = Win[(size_t)(R0 + r) * II + lane];

    float hold = 0.f;               // lane tracks row R0 + (lane&7)

    for (int j = 0; j < NROUND; ++j) {
        const int g = g0 + j;
        const float xv = x[(size_t)g * II + lane];  // in-loop: drains with poll
        float acc[8];
#pragma unroll
        for (int r = 0; r < 8; ++r) acc[r] = win[r] * xv;

        if (j > 0) {
            const float* hp = states + (size_t)(g - 1) * RR;
            float*    sb  = hb  + ((j - 1) & 1) * RR;
            _Float16* sh  = h16 + ((j - 1) & 1) * RR;
            // First pass: 4 coalesced dword poll loads per thread.
            float v0 = __hip_atomic_load(hp + tid,
                                         __ATOMIC_RELAXED, __HIP_MEMORY_SCOPE_AGENT);
            float v1 = __hip_atomic_load(hp + tid + 512,
                                         __ATOMIC_RELAXED, __HIP_MEMORY_SCOPE_AGENT);
            float v2 = __hip_atomic_load(hp + tid + 1024,
                                         __ATOMIC_RELAXED, __HIP_MEMORY_SCOPE_AGENT);
            float v3 = __hip_atomic_load(hp + tid + 1536,
                                         __ATOMIC_RELAXED, __HIP_MEMORY_SCOPE_AGENT);
            // Parity-range readiness: accept only my chunk's bias range.
            for (;;) {
                const bool r0 = fabsf(v0 - bias) <= 1.25f;
                const bool r1 = fabsf(v1 - bias) <= 1.25f;
                const bool r2 = fabsf(v2 - bias) <= 1.25f;
                const bool r3 = fabsf(v3 - bias) <= 1.25f;
                if (r0 && r1 && r2 && r3) break;
                if (!r0) v0 = __hip_atomic_load(hp + tid,
                                __ATOMIC_RELAXED, __HIP_MEMORY_SCOPE_AGENT);
                if (!r1) v1 = __hip_atomic_load(hp + tid + 512,
                                __ATOMIC_RELAXED, __HIP_MEMORY_SCOPE_AGENT);
                if (!r2) v2 = __hip_atomic_load(hp + tid + 1024,
                                __ATOMIC_RELAXED, __HIP_MEMORY_SCOPE_AGENT);
                if (!r3) v3 = __hip_atomic_load(hp + tid + 1536,
                                __ATOMIC_RELAXED, __HIP_MEMORY_SCOPE_AGENT);
            }
            // Publish raw biased values (f32) + f16 mirror for dot2 rows.
            sb[tid]        = v0;
            sb[tid + 512]  = v1;
            sb[tid + 1024] = v2;
            sb[tid + 1536] = v3;
            sh[tid]        = (_Float16)v0;
            sh[tid + 512]  = (_Float16)v1;
            sh[tid + 1024] = (_Float16)v2;
            sh[tid + 1536] = (_Float16)v3;
            __syncthreads();           // the ONLY barrier per round

            // Consume: 8x ds_read_b128 (h f32) vs register W (rows 0..3);
            // 8x ds_read_b64 (h f16) + 32x ds_read_b64 (W f16) into
            // v_dot2_f32_f16 (rows 4..7) -- 2 MACs/inst, f32 accumulate.
            const float4* sq  = (const float4*)sb;
            const uint2*  sq16= (const uint2*)sh;
#pragma unroll
            for (int m = 0; m < 8; ++m) {
                const float4 q = sq[lane + 64 * m];
                acc[0] += wq[0][m].x * q.x + wq[0][m].y * q.y
                        + wq[0][m].z * q.z + wq[0][m].w * q.w;
                acc[1] += wq[1][m].x * q.x + wq[1][m].y * q.y
                        + wq[1][m].z * q.z + wq[1][m].w * q.w;
                acc[2] += wq[2][m].x * q.x + wq[2][m].y * q.y
                        + wq[2][m].z * q.z + wq[2][m].w * q.w;
                acc[3] += wq[3][m].x * q.x + wq[3][m].y * q.y
                        + wq[3][m].z * q.z + wq[3][m].w * q.w;
                const uint2 qh = sq16[lane + 64 * m];
                const h2v qlo = __builtin_bit_cast(h2v, qh.x);
                const h2v qhi = __builtin_bit_cast(h2v, qh.y);
#pragma unroll
                for (int rr = 0; rr < 4; ++rr) {
                    const uint2 wp = wl2[(size_t)(wrow + rr) * 512 + lane + 64 * m];
                    acc[4 + rr] = __builtin_amdgcn_fdot2(
                        __builtin_bit_cast(h2v, wp.x), qlo, acc[4 + rr], false);
                    acc[4 + rr] = __builtin_amdgcn_fdot2(
                        __builtin_bit_cast(h2v, wp.y), qhi, acc[4 + rr], false);
                }
            }
        }

        // Reduce 8 rows: 3 fold stages + 3-level butterfly (10 shfls).
        {
            const float u01 = ((lane & 1) ? acc[1] : acc[0])
                            + __shfl_xor((lane & 1) ? acc[0] : acc[1], 1, 64);
            const float u23 = ((lane & 1) ? acc[3] : acc[2])
                            + __shfl_xor((lane & 1) ? acc[2] : acc[3], 1, 64);
            const float u45 = ((lane & 1) ? acc[5] : acc[4])
                            + __shfl_xor((lane & 1) ? acc[4] : acc[5], 1, 64);
            const float u67 = ((lane & 1) ? acc[7] : acc[6])
                            + __shfl_xor((lane & 1) ? acc[6] : acc[7], 1, 64);
            const float v03 = ((lane & 2) ? u23 : u01)
                            + __shfl_xor((lane & 2) ? u01 : u23, 2, 64);
            const float v47 = ((lane & 2) ? u67 : u45)
                            + __shfl_xor((lane & 2) ? u45 : u67, 2, 64);
            float a = ((lane & 4) ? v47 : v03)
                    + __shfl_xor((lane & 4) ? v03 : v47, 4, 64);
#pragma unroll
            for (int off = 8; off <= 32; off <<= 1)
                a += __shfl_xor(a, off, 64);
            // Bias-fold correction (only when biased h was consumed)
            if (j > 0) a -= twred;
            // tanh + leaky update for row R0 + (lane&7)
            float u = fminf(fmaxf(a, -20.f), 20.f);
            const float e  = __expf(2.f * u);
            const float th = (e - 1.f) / (e + 1.f);
            const float hn = 0.5f * hold + 0.5f * th;
            hold = hn;
            if (lane < 8)
                __hip_atomic_store(&states[(size_t)g * RR + R0 + lane], hn + bias,
                                   __ATOMIC_RELAXED, __HIP_MEMORY_SCOPE_AGENT);
        }
    }
}

// ---------------------------------------------------------------------------
// rowsum of fc1_w rows: rs[h] = sum_r fc1_w[h][r]
// ---------------------------------------------------------------------------
__global__ void k_rowsum(const float* __restrict__ fc1w, float* __restrict__ rs)
{
    const int h = blockIdx.x;
    const int tid = threadIdx.x;
    float a = 0.f;
    for (int r = tid; r < RR; r += 256) a += fc1w[(size_t)h * RR + r];
#pragma unroll
    for (int off = 1; off <= 32; off <<= 1) a += __shfl_xor(a, off, 64);
    __shared__ float red[4];
    if ((tid & 63) == 0) red[tid >> 6] = a;
    __syncthreads();
    if (tid == 0) rs[h] = red[0] + red[1] + red[2] + red[3];
}

// ---------------------------------------------------------------------------
// Mt[r][o] = sum_h fc2_w[o][h] * fc1_w[h][r]   (o padded to 64, zeros)
// ---------------------------------------------------------------------------
__global__ void k_mt(const float* __restrict__ fc1w,
                     const float* __restrict__ fc2w,
                     float* __restrict__ Mt)
{
    __shared__ float w2[OO][HH + 1];
    const int o = threadIdx.x;         // 64
    const int r = blockIdx.x;          // 2048
    for (int i = o; i < OO * HH; i += 64) w2[i / HH][i % HH] = fc2w[i];
    __syncthreads();
    float a = 0.f;
    if (o < OO) {
        for (int h = 0; h < HH; ++h)
            a += w2[o][h] * fc1w[(size_t)h * RR + r];
    }
    Mt[r * OP + o] = a;
}

// ---------------------------------------------------------------------------
// c2b[o] = fc2_b[o] + sum_h fc2_w[o][h]*fc1_b[h];  rm[o] = sum_h fc2w*rs[h]
// ---------------------------------------------------------------------------
__global__ void k_cc(const float* __restrict__ fc2w,
                     const float* __restrict__ fc2b,
                     const float* __restrict__ fc1b,
                     const float* __restrict__ rs,
                     float* __restrict__ c2b,
                     float* __restrict__ rm)
{
    const int o = threadIdx.x;  // 64
    float a = 0.f, b = 0.f;
    if (o < OO) {
        for (int h = 0; h < HH; ++h) {
            a += fc2w[o * HH + h] * fc1b[h];
            b += fc2w[o * HH + h] * rs[h];
        }
        a += fc2b[o];
    }
    c2b[o] = a;
    rm[o]  = b;
}

// ---------------------------------------------------------------------------
// out[t][o] = sum_r Mt[r][o] * states_biased[t][r] + c2b[o] - bias_t*rm[o]
// Chunk boundaries (2104 + 2040k) are NOT %16-aligned -> bias per element.
// ---------------------------------------------------------------------------
__global__ __launch_bounds__(256)
void out_kernel(const float* __restrict__ sb,
                const float* __restrict__ Mt,
                const float* __restrict__ c2b,
                const float* __restrict__ rm,
                float* __restrict__ out)
{
    const int tid = threadIdx.x;
    const int o   = tid & 63;
    const int tl  = tid >> 6;          // 0..3
    const int t0  = blockIdx.x * TT;
    float acc[4] = {0.f, 0.f, 0.f, 0.f};
    const float* s0 = sb + (size_t)t0 * RR;

    for (int r = 0; r < RR; r += 4) {
        float4 sv0 = *(const float4*)(s0 + (size_t)(tl + 0)  * RR + r);
        float4 sv1 = *(const float4*)(s0 + (size_t)(tl + 4)  * RR + r);
        float4 sv2 = *(const float4*)(s0 + (size_t)(tl + 8)  * RR + r);
        float4 sv3 = *(const float4*)(s0 + (size_t)(tl + 12) * RR + r);
        float m0 = Mt[(r + 0) * OP + o];
        float m1 = Mt[(r + 1) * OP + o];
        float m2 = Mt[(r + 2) * OP + o];
        float m3 = Mt[(r + 3) * OP + o];
        acc[0] += m0 * sv0.x + m1 * sv0.y + m2 * sv0.z + m3 * sv0.w;
        acc[1] += m0 * sv1.x + m1 * sv1.y + m2 * sv1.z + m3 * sv1.w;
        acc[2] += m0 * sv2.x + m1 * sv2.y + m2 * sv2.z + m3 * sv2.w;
        acc[3] += m0 * sv3.x + m1 * sv3.y + m2 * sv3.z + m3 * sv3.w;
    }
    if (o < OO) {
        const float cb = c2b[o];
        const float rv = rm[o];
#pragma unroll
        for (int m = 0; m < 4; ++m) {
            const int t = t0 + tl + 4 * m;
            const int ch = (t < C0LEN) ? 0 : (1 + (t - C0LEN) / CLEN);
            const float bias = (ch & 1) ? 6.0f : 2.0f;
            out[(size_t)t * OO + o] = acc[m] + cb - bias * rv;
        }
    }
}

extern "C" void kernel_launch(void* const* d_in, const int* in_sizes, int n_in,
                              void* d_out, int out_size, void* d_ws, size_t ws_size,
                              hipStream_t stream)
{
    const float* x    = (const float*)d_in[0];
    const float* Win  = (const float*)d_in[1];
    const float* W    = (const float*)d_in[2];
    const float* fc1w = (const float*)d_in[3];
    const float* fc1b = (const float*)d_in[4];
    const float* fc2w = (const float*)d_in[5];
    const float* fc2b = (const float*)d_in[6];
    float* out = (float*)d_out;

    if (ws_size < WS_NEED) return;

    char*  ws     = (char*)d_ws;
    float* states = (float*)ws;
    float* Mt     = (float*)(ws + MT_OFF);
    float* c2b    = (float*)(ws + C2B_OFF);
    float* rm     = (float*)(ws + RM_OFF);
    float* rs     = (float*)(ws + RS_OFF);

    // Raise the dynamic-LDS cap once (not a stream op; graph-capture safe).
    static bool attr_done = false;
    if (!attr_done) {
        hipFuncSetAttribute(reinterpret_cast<const void*>(scan_kernel),
                            hipFuncAttributeMaxDynamicSharedMemorySize,
                            SMEM_BYTES);
        attr_done = true;
    }

    // Sentinel init: 0.0f is outside both bias ranges -> "not ready".
    hipMemsetAsync(states, 0, STATES_BYTES, stream);

    k_rowsum<<<HH, 256, 0, stream>>>(fc1w, rs);
    k_mt<<<RR, 64, 0, stream>>>(fc1w, fc2w, Mt);
    k_cc<<<1, 64, 0, stream>>>(fc2w, fc2b, fc1b, rs, c2b, rm);

    scan_kernel<<<NBLK, NTHR, SMEM_BYTES, stream>>>(x, Win, W, states);

    out_kernel<<<SS / TT, 256, 0, stream>>>(states, Mt, c2b, rm, out);
}

// Round 5
// 6209.705 us; speedup vs baseline: 4.7590x; 1.0528x over previous
//
#include <hip/hip_runtime.h>
#include <hip/hip_fp16.h>
#include <math.h>

// Echo-state network: sequential scan with dense 2048x2048 matvec per step.
// R25 -- f16-only h transport in LDS: delete the redundant f32 h buffer.
//
// R24 post-mortem (passed, scan 6.33ms, parity with 4-chunk baseline):
// fdot2 fixed consume VALU (VALUBusy 34.5->28.2), but the round is 3.01us
// vs baseline 1.54. LDS-pipe arithmetic locates the cost: consume reads
// 448B/thread (8xb128 f32-h + 8xb64 f16-h + 32xb64 f16-W) = 229KB/CU/round
// / ~85B/cy (m134 ds_read ceiling) ~ 2700cy vs baseline's 770cy.
// The f32 h buffer is redundant: R24 PROVED f16-rounded biased-h operands
// are numerically free (absmax bit-identical). R25 consumes f16 h for ALL
// 8 rows: rows 0..3 via 4x v_cvt_f32_f16 per m + the proven fp32 register-W
// FMAs; rows 4..7 via fdot2 as in R24. Deletes 128B/thr of b128 reads and
// the f32 publish: LDS reads 448->320B/thr (-29%, ~-800cy/round).
// One change class; zero new constructs; transport untouched.
//
// Error model (proven class): consume uses round_f16(h+bias); the bias-fold
// a -= twred removes bias*sum(W row) exactly; residual is sum(W*eps) ~1e-4
// pre-tanh/step -- identical to R24's rows 4..7 path, which passed with
// absmax unchanged.
//
// Carried from R24/R22: 8 chunks x 32 blocks x 512 thr; rows 0..3/wave W
// fp32 in regs (PIN4, proven AGPR placement), rows 4..7/wave W f16 in LDS;
// twred bias-fold post-butterfly; C0LEN=2104/CLEN=2040/WUP=64 ->
// NROUND=2104; parity bias-tags 2/6; in-loop x load; block-coop agent poll
// + straggler retry; publish + ONE barrier; fold+butterfly reduce; tanh;
// agent store; fc1/fc2 collapse: out = states_b @ Mt + (c2b - bias_t*rm).

#define SS 16384
#define II 64
#define RR 2048
#define HH 128
#define OO 50
#define OP 64          // padded output dim
#define NROUND 2104    // rounds per chunk (uniform)
#define C0LEN 2104     // chunk 0 output length
#define CLEN 2040      // chunks 1-7 output length
#define WUP 64         // warm-up steps for chunks 1-7
#define NBLK 256
#define NTHR 512
#define TT 16          // timesteps per block in out_kernel

// W f16 rows (128KB) + h f16 dbuf (8KB)
#define SMEM_BYTES (32 * RR * 2 + 2 * RR * 2)   // 139264

static const size_t STATES_BYTES = (size_t)SS * RR * 4;        // 134217728
static const size_t MT_OFF  = STATES_BYTES;
static const size_t C2B_OFF = MT_OFF + (size_t)RR * OP * 4;    // +524288
static const size_t RM_OFF  = C2B_OFF + 256;
static const size_t RS_OFF  = RM_OFF + 256;
static const size_t WS_NEED = RS_OFF + 512 + 256;

typedef _Float16 h2v __attribute__((ext_vector_type(2)));

// Opaque register pin for LOOP-INVARIANT values (W fragments) only.
// NEVER on in-loop load results (forces a waitcnt at the pin site -- R6/R15).
#define PIN4(q) asm volatile("" : "+v"((q).x), "+v"((q).y), "+v"((q).z), "+v"((q).w))

// ---------------------------------------------------------------------------
// Persistent chunked scan. chunk = blk&7, brow = blk>>3.
// Wave w owns rows R0 = brow*64 + w*8 .. R0+7.
//   rows R0+0..3: W fp32 in registers, lane l holds cols {4l+j+256m}.
//   rows R0+4..7: W f16 in LDS, same column mapping, wave-private.
// h transport: f16 mirror only, [2][RR] dbuf.
// ---------------------------------------------------------------------------
__global__ __launch_bounds__(NTHR, 2)
void scan_kernel(const float* __restrict__ x,
                 const float* __restrict__ Win,
                 const float* __restrict__ W,
                 float* __restrict__ states)
{
    const int tid   = threadIdx.x;
    const int blk   = blockIdx.x;
    const int wave  = tid >> 6;             // 0..7
    const int lane  = tid & 63;
    const int chunk = blk & 7;
    const int brow  = blk >> 3;             // 0..31
    const int R0    = brow * 64 + wave * 8;

    const float bias = (chunk & 1) ? 6.0f : 2.0f;
    const int g0 = CLEN * chunk;            // 0 for chunk 0; warm-up start else

    extern __shared__ char smem_raw[];
    uint2*    wl2 = (uint2*)smem_raw;                       // 32 x 512 uint2
    _Float16* h16 = (_Float16*)(smem_raw + 32 * RR * 2);    // [2][RR]

    // --- Register W: rows 0..3, byte-identical to proven baseline ---
    float4 wq[4][8];
#pragma unroll
    for (int r = 0; r < 4; ++r)
#pragma unroll
        for (int m = 0; m < 8; ++m) {
            wq[r][m] = *(const float4*)&W[(size_t)(R0 + r) * RR + 4 * lane + 256 * m];
            PIN4(wq[r][m]);
        }

    // Per-row bias-fold partials (reg rows: exact fp32 values)
    float twp[8];
#pragma unroll
    for (int r = 0; r < 4; ++r) {
        float s = 0.f;
#pragma unroll
        for (int m = 0; m < 8; ++m)
            s += wq[r][m].x + wq[r][m].y + wq[r][m].z + wq[r][m].w;
        twp[r] = s;
    }

    // --- LDS W: rows 4..7, packed f16, wave-private (no barrier needed) ---
    const int wrow = wave * 4;              // my first LDS row slot
#pragma unroll
    for (int rr = 0; rr < 4; ++rr) {
        float s = 0.f;
#pragma unroll
        for (int m = 0; m < 8; ++m) {
            const float4 wv = *(const float4*)&W[(size_t)(R0 + 4 + rr) * RR + 4 * lane + 256 * m];
            const __half h0 = __float2half_rn(wv.x);
            const __half h1 = __float2half_rn(wv.y);
            const __half h2 = __float2half_rn(wv.z);
            const __half h3 = __float2half_rn(wv.w);
            uint2 p;
            p.x = __builtin_bit_cast(unsigned int, __halves2half2(h0, h1));
            p.y = __builtin_bit_cast(unsigned int, __halves2half2(h2, h3));
            wl2[(size_t)(wrow + rr) * 512 + lane + 64 * m] = p;
            // tw from the ROUNDED values (what the dot product will use)
            s += __half2float(h0) + __half2float(h1)
               + __half2float(h2) + __half2float(h3);
        }
        twp[4 + rr] = s;
    }

    // Pre-reduce tw across lanes with the SAME fold+butterfly as the main
    // loop: after this, every lane holds bias * rowsum(W[R0+(lane&7)]).
    float twred;
    {
        const float u01 = ((lane & 1) ? twp[1] : twp[0])
                        + __shfl_xor((lane & 1) ? twp[0] : twp[1], 1, 64);
        const float u23 = ((lane & 1) ? twp[3] : twp[2])
                        + __shfl_xor((lane & 1) ? twp[2] : twp[3], 1, 64);
        const float u45 = ((lane & 1) ? twp[5] : twp[4])
                        + __shfl_xor((lane & 1) ? twp[4] : twp[5], 1, 64);
        const float u67 = ((lane & 1) ? twp[7] : twp[6])
                        + __shfl_xor((lane & 1) ? twp[6] : twp[7], 1, 64);
        const float v03 = ((lane & 2) ? u23 : u01)
                        + __shfl_xor((lane & 2) ? u01 : u23, 2, 64);
        const float v47 = ((lane & 2) ? u67 : u45)
                        + __shfl_xor((lane & 2) ? u45 : u67, 2, 64);
        float a = ((lane & 4) ? v47 : v03)
                + __shfl_xor((lane & 4) ? v03 : v47, 4, 64);
#pragma unroll
        for (int off = 8; off <= 32; off <<= 1)
            a += __shfl_xor(a, off, 64);
        twred = bias * a;
    }

    // Input projection fragments
    float win[8];
#pragma unroll
    for (int r = 0; r < 8; ++r)
        win[r] = Win[(size_t)(R0 + r) * II + lane];

    float hold = 0.f;               // lane tracks row R0 + (lane&7)

    for (int j = 0; j < NROUND; ++j) {
        const int g = g0 + j;
        const float xv = x[(size_t)g * II + lane];  // in-loop: drains with poll
        float acc[8];
#pragma unroll
        for (int r = 0; r < 8; ++r) acc[r] = win[r] * xv;

        if (j > 0) {
            const float* hp = states + (size_t)(g - 1) * RR;
            _Float16* sh = h16 + ((j - 1) & 1) * RR;
            // First pass: 4 coalesced dword poll loads per thread.
            float v0 = __hip_atomic_load(hp + tid,
                                         __ATOMIC_RELAXED, __HIP_MEMORY_SCOPE_AGENT);
            float v1 = __hip_atomic_load(hp + tid + 512,
                                         __ATOMIC_RELAXED, __HIP_MEMORY_SCOPE_AGENT);
            float v2 = __hip_atomic_load(hp + tid + 1024,
                                         __ATOMIC_RELAXED, __HIP_MEMORY_SCOPE_AGENT);
            float v3 = __hip_atomic_load(hp + tid + 1536,
                                         __ATOMIC_RELAXED, __HIP_MEMORY_SCOPE_AGENT);
            // Parity-range readiness: accept only my chunk's bias range.
            for (;;) {
                const bool r0 = fabsf(v0 - bias) <= 1.25f;
                const bool r1 = fabsf(v1 - bias) <= 1.25f;
                const bool r2 = fabsf(v2 - bias) <= 1.25f;
                const bool r3 = fabsf(v3 - bias) <= 1.25f;
                if (r0 && r1 && r2 && r3) break;
                if (!r0) v0 = __hip_atomic_load(hp + tid,
                                __ATOMIC_RELAXED, __HIP_MEMORY_SCOPE_AGENT);
                if (!r1) v1 = __hip_atomic_load(hp + tid + 512,
                                __ATOMIC_RELAXED, __HIP_MEMORY_SCOPE_AGENT);
                if (!r2) v2 = __hip_atomic_load(hp + tid + 1024,
                                __ATOMIC_RELAXED, __HIP_MEMORY_SCOPE_AGENT);
                if (!r3) v3 = __hip_atomic_load(hp + tid + 1536,
                                __ATOMIC_RELAXED, __HIP_MEMORY_SCOPE_AGENT);
            }
            // Publish f16-rounded biased h only (4 cvt + 4 ds_write_b16).
            sh[tid]        = (_Float16)v0;
            sh[tid + 512]  = (_Float16)v1;
            sh[tid + 1024] = (_Float16)v2;
            sh[tid + 1536] = (_Float16)v3;
            __syncthreads();           // the ONLY barrier per round

            // Consume: 8x ds_read_b64 (h f16) + 32x ds_read_b64 (W f16).
            // Rows 0..3: cvt h->f32 (4/m) vs fp32 register W.
            // Rows 4..7: v_dot2_f32_f16 vs LDS f16 W.
            const uint2* sq16 = (const uint2*)sh;
#pragma unroll
            for (int m = 0; m < 8; ++m) {
                const uint2 qh = sq16[lane + 64 * m];
                const h2v qlo = __builtin_bit_cast(h2v, qh.x);
                const h2v qhi = __builtin_bit_cast(h2v, qh.y);
                const float qx = (float)qlo[0];
                const float qy = (float)qlo[1];
                const float qz = (float)qhi[0];
                const float qw = (float)qhi[1];
                acc[0] += wq[0][m].x * qx + wq[0][m].y * qy
                        + wq[0][m].z * qz + wq[0][m].w * qw;
                acc[1] += wq[1][m].x * qx + wq[1][m].y * qy
                        + wq[1][m].z * qz + wq[1][m].w * qw;
                acc[2] += wq[2][m].x * qx + wq[2][m].y * qy
                        + wq[2][m].z * qz + wq[2][m].w * qw;
                acc[3] += wq[3][m].x * qx + wq[3][m].y * qy
                        + wq[3][m].z * qz + wq[3][m].w * qw;
#pragma unroll
                for (int rr = 0; rr < 4; ++rr) {
                    const uint2 wp = wl2[(size_t)(wrow + rr) * 512 + lane + 64 * m];
                    acc[4 + rr] = __builtin_amdgcn_fdot2(
                        __builtin_bit_cast(h2v, wp.x), qlo, acc[4 + rr], false);
                    acc[4 + rr] = __builtin_amdgcn_fdot2(
                        __builtin_bit_cast(h2v, wp.y), qhi, acc[4 + rr], false);
                }
            }
        }

        // Reduce 8 rows: 3 fold stages + 3-level butterfly (10 shfls).
        {
            const float u01 = ((lane & 1) ? acc[1] : acc[0])
                            + __shfl_xor((lane & 1) ? acc[0] : acc[1], 1, 64);
            const float u23 = ((lane & 1) ? acc[3] : acc[2])
                            + __shfl_xor((lane & 1) ? acc[2] : acc[3], 1, 64);
            const float u45 = ((lane & 1) ? acc[5] : acc[4])
                            + __shfl_xor((lane & 1) ? acc[4] : acc[5], 1, 64);
            const float u67 = ((lane & 1) ? acc[7] : acc[6])
                            + __shfl_xor((lane & 1) ? acc[6] : acc[7], 1, 64);
            const float v03 = ((lane & 2) ? u23 : u01)
                            + __shfl_xor((lane & 2) ? u01 : u23, 2, 64);
            const float v47 = ((lane & 2) ? u67 : u45)
                            + __shfl_xor((lane & 2) ? u45 : u67, 2, 64);
            float a = ((lane & 4) ? v47 : v03)
                    + __shfl_xor((lane & 4) ? v03 : v47, 4, 64);
#pragma unroll
            for (int off = 8; off <= 32; off <<= 1)
                a += __shfl_xor(a, off, 64);
            // Bias-fold correction (only when biased h was consumed)
            if (j > 0) a -= twred;
            // tanh + leaky update for row R0 + (lane&7)
            float u = fminf(fmaxf(a, -20.f), 20.f);
            const float e  = __expf(2.f * u);
            const float th = (e - 1.f) / (e + 1.f);
            const float hn = 0.5f * hold + 0.5f * th;
            hold = hn;
            if (lane < 8)
                __hip_atomic_store(&states[(size_t)g * RR + R0 + lane], hn + bias,
                                   __ATOMIC_RELAXED, __HIP_MEMORY_SCOPE_AGENT);
        }
    }
}

// ---------------------------------------------------------------------------
// rowsum of fc1_w rows: rs[h] = sum_r fc1_w[h][r]
// ---------------------------------------------------------------------------
__global__ void k_rowsum(const float* __restrict__ fc1w, float* __restrict__ rs)
{
    const int h = blockIdx.x;
    const int tid = threadIdx.x;
    float a = 0.f;
    for (int r = tid; r < RR; r += 256) a += fc1w[(size_t)h * RR + r];
#pragma unroll
    for (int off = 1; off <= 32; off <<= 1) a += __shfl_xor(a, off, 64);
    __shared__ float red[4];
    if ((tid & 63) == 0) red[tid >> 6] = a;
    __syncthreads();
    if (tid == 0) rs[h] = red[0] + red[1] + red[2] + red[3];
}

// ---------------------------------------------------------------------------
// Mt[r][o] = sum_h fc2_w[o][h] * fc1_w[h][r]   (o padded to 64, zeros)
// ---------------------------------------------------------------------------
__global__ void k_mt(const float* __restrict__ fc1w,
                     const float* __restrict__ fc2w,
                     float* __restrict__ Mt)
{
    __shared__ float w2[OO][HH + 1];
    const int o = threadIdx.x;         // 64
    const int r = blockIdx.x;          // 2048
    for (int i = o; i < OO * HH; i += 64) w2[i / HH][i % HH] = fc2w[i];
    __syncthreads();
    float a = 0.f;
    if (o < OO) {
        for (int h = 0; h < HH; ++h)
            a += w2[o][h] * fc1w[(size_t)h * RR + r];
    }
    Mt[r * OP + o] = a;
}

// ---------------------------------------------------------------------------
// c2b[o] = fc2_b[o] + sum_h fc2_w[o][h]*fc1_b[h];  rm[o] = sum_h fc2w*rs[h]
// ---------------------------------------------------------------------------
__global__ void k_cc(const float* __restrict__ fc2w,
                     const float* __restrict__ fc2b,
                     const float* __restrict__ fc1b,
                     const float* __restrict__ rs,
                     float* __restrict__ c2b,
                     float* __restrict__ rm)
{
    const int o = threadIdx.x;  // 64
    float a = 0.f, b = 0.f;
    if (o < OO) {
        for (int h = 0; h < HH; ++h) {
            a += fc2w[o * HH + h] * fc1b[h];
            b += fc2w[o * HH + h] * rs[h];
        }
        a += fc2b[o];
    }
    c2b[o] = a;
    rm[o]  = b;
}

// ---------------------------------------------------------------------------
// out[t][o] = sum_r Mt[r][o] * states_biased[t][r] + c2b[o] - bias_t*rm[o]
// Chunk boundaries (2104 + 2040k) are NOT %16-aligned -> bias per element.
// ---------------------------------------------------------------------------
__global__ __launch_bounds__(256)
void out_kernel(const float* __restrict__ sb,
                const float* __restrict__ Mt,
                const float* __restrict__ c2b,
                const float* __restrict__ rm,
                float* __restrict__ out)
{
    const int tid = threadIdx.x;
    const int o   = tid & 63;
    const int tl  = tid >> 6;          // 0..3
    const int t0  = blockIdx.x * TT;
    float acc[4] = {0.f, 0.f, 0.f, 0.f};
    const float* s0 = sb + (size_t)t0 * RR;

    for (int r = 0; r < RR; r += 4) {
        float4 sv0 = *(const float4*)(s0 + (size_t)(tl + 0)  * RR + r);
        float4 sv1 = *(const float4*)(s0 + (size_t)(tl + 4)  * RR + r);
        float4 sv2 = *(const float4*)(s0 + (size_t)(tl + 8)  * RR + r);
        float4 sv3 = *(const float4*)(s0 + (size_t)(tl + 12) * RR + r);
        float m0 = Mt[(r + 0) * OP + o];
        float m1 = Mt[(r + 1) * OP + o];
        float m2 = Mt[(r + 2) * OP + o];
        float m3 = Mt[(r + 3) * OP + o];
        acc[0] += m0 * sv0.x + m1 * sv0.y + m2 * sv0.z + m3 * sv0.w;
        acc[1] += m0 * sv1.x + m1 * sv1.y + m2 * sv1.z + m3 * sv1.w;
        acc[2] += m0 * sv2.x + m1 * sv2.y + m2 * sv2.z + m3 * sv2.w;
        acc[3] += m0 * sv3.x + m1 * sv3.y + m2 * sv3.z + m3 * sv3.w;
    }
    if (o < OO) {
        const float cb = c2b[o];
        const float rv = rm[o];
#pragma unroll
        for (int m = 0; m < 4; ++m) {
            const int t = t0 + tl + 4 * m;
            const int ch = (t < C0LEN) ? 0 : (1 + (t - C0LEN) / CLEN);
            const float bias = (ch & 1) ? 6.0f : 2.0f;
            out[(size_t)t * OO + o] = acc[m] + cb - bias * rv;
        }
    }
}

extern "C" void kernel_launch(void* const* d_in, const int* in_sizes, int n_in,
                              void* d_out, int out_size, void* d_ws, size_t ws_size,
                              hipStream_t stream)
{
    const float* x    = (const float*)d_in[0];
    const float* Win  = (const float*)d_in[1];
    const float* W    = (const float*)d_in[2];
    const float* fc1w = (const float*)d_in[3];
    const float* fc1b = (const float*)d_in[4];
    const float* fc2w = (const float*)d_in[5];
    const float* fc2b = (const float*)d_in[6];
    float* out = (float*)d_out;

    if (ws_size < WS_NEED) return;

    char*  ws     = (char*)d_ws;
    float* states = (float*)ws;
    float* Mt     = (float*)(ws + MT_OFF);
    float* c2b    = (float*)(ws + C2B_OFF);
    float* rm     = (float*)(ws + RM_OFF);
    float* rs     = (float*)(ws + RS_OFF);

    // Raise the dynamic-LDS cap once (not a stream op; graph-capture safe).
    static bool attr_done = false;
    if (!attr_done) {
        hipFuncSetAttribute(reinterpret_cast<const void*>(scan_kernel),
                            hipFuncAttributeMaxDynamicSharedMemorySize,
                            SMEM_BYTES);
        attr_done = true;
    }

    // Sentinel init: 0.0f is outside both bias ranges -> "not ready".
    hipMemsetAsync(states, 0, STATES_BYTES, stream);

    k_rowsum<<<HH, 256, 0, stream>>>(fc1w, rs);
    k_mt<<<RR, 64, 0, stream>>>(fc1w, fc2w, Mt);
    k_cc<<<1, 64, 0, stream>>>(fc2w, fc2b, fc1b, rs, c2b, rm);

    scan_kernel<<<NBLK, NTHR, SMEM_BYTES, stream>>>(x, Win, W, states);

    out_kernel<<<SS / TT, 256, 0, stream>>>(states, Mt, c2b, rm, out);
}